// Round 7
// baseline (257.243 us; speedup 1.0000x reference)
//
#include <hip/hip_runtime.h>
#include <cstdint>
#include <cstddef>

// Problem constants
#define NB   32    // query batch
#define NSUP 25    // support images
#define KCLS 5     // classes
#define NC   512   // input channels
#define ND   128   // dk = dv
#define NP   196   // h*w
#define JS   208   // per-support padded spatial (13*16)
#define NIMG 57    // 32 query + 25 support
#define SHIFT 8.0f // fixed logit shift (softmax-invariant overflow guard)

typedef __attribute__((ext_vector_type(8))) short short8;   // 8 x bf16 (4 VGPRs)
typedef __attribute__((ext_vector_type(4))) float floatx4;  // MFMA C/D

__device__ inline short f2bf(float x) {
  union { float f; uint32_t u; } v; v.f = x;
  uint32_t r = (v.u + 0x7FFFu + ((v.u >> 16) & 1u)) >> 16;  // RNE
  return (short)(r & 0xFFFFu);
}
__device__ inline float bf2f(short h) {
  union { uint32_t u; float f; } v; v.u = ((uint32_t)(uint16_t)h) << 16;
  return v.f;
}
__device__ inline uint32_t pk2(float a, float b) {
  return (uint32_t)(uint16_t)f2bf(a) | ((uint32_t)(uint16_t)f2bf(b) << 16);
}

// ---------------------------------------------------------------------------
// Kernel 0: fp32 -> bf16 hi/lo convert + transpose.
//   Xhi/Xlo[img][pp:208][c:512] (c-contig; pad rows = copy of row 195)
//   Whi/Wlo[mat][d:128][c:512]
// grid = 57*16 + 2 = 914 blocks x 256 threads.
// R7: store phase emits 16-B short8 stores (8 c per thread) instead of 2-B
// scalars — the R6 conv was store-width-bound.
// ---------------------------------------------------------------------------
__global__ __launch_bounds__(256) void conv_kernel(
    const float* __restrict__ supp, const float* __restrict__ qry,
    const float* __restrict__ Wqk, const float* __restrict__ Wv,
    uint16_t* __restrict__ Xhi, uint16_t* __restrict__ Xlo,
    uint16_t* __restrict__ Whi, uint16_t* __restrict__ Wlo)
{
  const int bx = blockIdx.x, tid = (int)threadIdx.x;
  if (bx >= 912) {                    // W conversion
    const int mat = bx - 912;
    const float* __restrict__ W = mat ? Wv : Wqk;
    uint16_t* dh = Whi + (size_t)mat * ND * NC;
    uint16_t* dl = Wlo + (size_t)mat * ND * NC;
    for (int i = tid; i < ND * NC; i += 256) {
      const float x = W[i];
      const short h = f2bf(x);
      dh[i] = (uint16_t)h;
      dl[i] = (uint16_t)f2bf(x - bf2f(h));
    }
    return;
  }
  __shared__ float lds[32 * 209];
  const int img = bx >> 4, c0 = (bx & 15) * 32;
  const float* __restrict__ X = (img < NB)
      ? (qry  + (size_t)img * NC * NP)
      : (supp + (size_t)(img - NB) * NC * NP);
  for (int idx = tid; idx < 32 * JS; idx += 256) {   // read [c][p] coalesced
    const int cc = idx / JS, pp = idx - cc * JS;
    lds[cc * 209 + pp] = X[(c0 + cc) * NP + (pp < NP ? pp : NP - 1)];
  }
  __syncthreads();
  for (int idx = tid; idx < 4 * JS; idx += 256) {    // 8-c groups, 16-B stores
    const int cg = idx & 3, pp = idx >> 2;
    short8 hv, lv;
    #pragma unroll
    for (int i = 0; i < 8; ++i) {
      const float x = lds[(cg * 8 + i) * 209 + pp];
      const short h = f2bf(x);
      hv[i] = h;
      lv[i] = f2bf(x - bf2f(h));
    }
    const size_t o = ((size_t)img * JS + pp) * NC + c0 + cg * 8;
    *(short8*)(Xhi + o) = hv;
    *(short8*)(Xlo + o) = lv;
  }
}

// ---------------------------------------------------------------------------
// Kernel 1: merged projection GEMM, full K=512 per wave, d-split 4-way.
// Block = (img, p-tile16), 4 waves = 4 d-quads (32 d each); X loads L1-shared.
// grid = 57*13 = 741 blocks x 256 threads = 2964 waves.
//   QK (1-term):  A=X(m=p), B=Wqk(n=d)  -> bf16 Qt[b][p<196][d] / Kt[n][p:208][d]
//   V  (3-term):  A=Wv(m=d), B=X(n=p)   -> bf16 Vt[n][d][p:208] / fp32 outVq[b][d][p]
// ---------------------------------------------------------------------------
__global__ __launch_bounds__(256) void gemm_kernel(
    const uint16_t* __restrict__ Xhi, const uint16_t* __restrict__ Xlo,
    const uint16_t* __restrict__ Whi, const uint16_t* __restrict__ Wlo,
    uint16_t* __restrict__ Qt, uint16_t* __restrict__ Kt,
    uint16_t* __restrict__ Vt, float* __restrict__ outVq)
{
  const int bx = blockIdx.x;
  const int t16 = bx % 13, img = bx / 13;
  const int tid = (int)threadIdx.x;
  const int w = tid >> 6, lane = tid & 63, ln = lane & 15, q = lane >> 4;
  const int d0 = w * 32;

  const size_t xrow = ((size_t)img * JS + t16 * 16 + ln) * NC + q * 8;
  floatx4 aQ[2], aV[2];
  #pragma unroll
  for (int nt = 0; nt < 2; ++nt) {
    aQ[nt] = (floatx4){0.f, 0.f, 0.f, 0.f};
    aV[nt] = (floatx4){0.f, 0.f, 0.f, 0.f};
  }

  for (int ks = 0; ks < 16; ++ks) {
    const int co = ks * 32;
    const short8 xh = *(const short8*)(Xhi + xrow + co);
    const short8 xl = *(const short8*)(Xlo + xrow + co);
    #pragma unroll
    for (int nt = 0; nt < 2; ++nt) {
      const size_t wr = (size_t)(d0 + nt * 16 + ln) * NC + co + q * 8;
      const short8 wqh = *(const short8*)(Whi + wr);
      aQ[nt] = __builtin_amdgcn_mfma_f32_16x16x32_bf16(xh, wqh, aQ[nt], 0, 0, 0);
      const short8 wvh = *(const short8*)(Whi + (size_t)ND * NC + wr);
      const short8 wvl = *(const short8*)(Wlo + (size_t)ND * NC + wr);
      aV[nt] = __builtin_amdgcn_mfma_f32_16x16x32_bf16(wvh, xh, aV[nt], 0, 0, 0);
      aV[nt] = __builtin_amdgcn_mfma_f32_16x16x32_bf16(wvh, xl, aV[nt], 0, 0, 0);
      aV[nt] = __builtin_amdgcn_mfma_f32_16x16x32_bf16(wvl, xh, aV[nt], 0, 0, 0);
    }
  }

  // QK: D row = p = t16*16+q*4+rr, col = d = d0+nt*16+ln
  if (img < NB) {
    #pragma unroll
    for (int nt = 0; nt < 2; ++nt)
      #pragma unroll
      for (int rr = 0; rr < 4; ++rr) {
        const int p = t16 * 16 + q * 4 + rr;
        if (p < NP)
          Qt[((size_t)img * NP + p) * ND + d0 + nt * 16 + ln] = (uint16_t)f2bf(aQ[nt][rr]);
      }
  } else {
    const int n = img - NB;
    #pragma unroll
    for (int nt = 0; nt < 2; ++nt)
      #pragma unroll
      for (int rr = 0; rr < 4; ++rr) {
        const int p = t16 * 16 + q * 4 + rr;        // 0..207, pads masked in attn
        Kt[((size_t)n * JS + p) * ND + d0 + nt * 16 + ln] = (uint16_t)f2bf(aQ[nt][rr]);
      }
  }
  // V: D row = d = d0+nt*16+q*4+rr, col = p = t16*16+ln
  const int p = t16 * 16 + ln;
  if (img < NB) {
    if (p < NP) {
      #pragma unroll
      for (int nt = 0; nt < 2; ++nt)
        #pragma unroll
        for (int rr = 0; rr < 4; ++rr)
          outVq[((size_t)img * ND + d0 + nt * 16 + q * 4 + rr) * NP + p] = aV[nt][rr];
    }
  } else {
    const int n = img - NB;
    #pragma unroll
    for (int nt = 0; nt < 2; ++nt)
      #pragma unroll
      for (int rr = 0; rr < 4; ++rr)
        Vt[((size_t)n * ND + d0 + nt * 16 + q * 4 + rr) * JS + p] = (uint16_t)f2bf(aV[nt][rr]);
  }
}

// ---------------------------------------------------------------------------
// Kernel 2: per-class masked attention, 16x16x32 MFMA (verified layouts).
// Block = (b, kc, p-tile16), 8 waves j-split (singleton batch): 2080 x 512
// = 16640 waves; per-wave chain ~4 chunks. Core chunk body is R6-verbatim.
// 8-way merge via one 64-KB LDS exchange + single barrier.
// ---------------------------------------------------------------------------
__global__ __launch_bounds__(512, 4) void attn_kernel(
    const uint16_t* __restrict__ Qt, const uint16_t* __restrict__ Kt,
    const uint16_t* __restrict__ Vt, const int* __restrict__ labels,
    float* __restrict__ out)
{
  __shared__ __align__(16) float mergeAcc[8][8][256];  // [src wave][d-tile][lane*4]
  __shared__ float sS[8][16];

  const int bx = blockIdx.x;              // 2080 = 32*65
  const int b = bx / 65, rem = bx % 65;
  const int kc = rem / 13, pt = rem % 13;
  const int p0 = pt * 16;
  const int tid = (int)threadIdx.x;
  const int w = tid >> 6, lane = tid & 63, ln = lane & 15, q = lane >> 4;

  // class-support list packed in a register (6 bits/slot) via ballot
  const int myl = (lane < NSUP) ? labels[lane] : -1;
  unsigned long long m = __ballot(myl == kc);
  int clsPack = 0;
  #pragma unroll
  for (int s = 0; s < 5; ++s) {
    const int n = (m != 0ull) ? (int)__builtin_ctzll(m) : 0;
    clsPack |= n << (6 * s);
    m &= (m - 1);
  }

  // Q B-frags (resident): B[n=p][k=d]
  short8 aq[4];
  {
    int p = p0 + ln; if (p > NP - 1) p = NP - 1;
    const uint16_t* base = Qt + ((size_t)b * NP + p) * ND + q * 8;
    #pragma unroll
    for (int ks = 0; ks < 4; ++ks) aq[ks] = *(const short8*)(base + ks * 32);
  }

  floatx4 acc[8];
  #pragma unroll
  for (int dt = 0; dt < 8; ++dt) acc[dt] = (floatx4){0.f, 0.f, 0.f, 0.f};
  float Ssum = 0.f;

  const int alo = (ln + ((q & 1) << 5)) << 2;  // bpermute byte addr (R4-verified)
  const bool hiTile = (q >= 2);

  for (int it = w; it < 33; it += 8) {         // this wave's 32-col chunks
    // --- V B-frags: B[n=d][k=j] ---
    const int cc = it * 32 + q * 8;
    int s2 = cc / JS, j2 = cc - s2 * JS;
    if (s2 > 4) { s2 = 4; j2 = 192; }          // pad region: weights are 0
    const int n2 = (clsPack >> (6 * s2)) & 63;
    short8 av[8];
    #pragma unroll
    for (int dt = 0; dt < 8; ++dt)
      av[dt] = *(const short8*)(Vt + ((size_t)n2 * ND + dt * 16 + ln) * JS + j2);

    // --- K A-frags: A[m=j][k=d], per 16-col tile ---
    short8 bk[2][4];
    int jb[2]; bool tval[2];
    #pragma unroll
    for (int t = 0; t < 2; ++t) {
      const int tile16 = it * 2 + t;
      int s = tile16 / 13;
      const int j0 = (tile16 - s * 13) * 16;
      tval[t] = (s < 5); jb[t] = j0;
      if (s > 4) s = 4;
      const int n = (clsPack >> (6 * s)) & 63;
      const uint16_t* kp = Kt + ((size_t)n * JS + j0 + ln) * ND + q * 8;
      #pragma unroll
      for (int ks = 0; ks < 4; ++ks) bk[t][ks] = *(const short8*)(kp + ks * 32);
    }

    // --- QK as S^T, exp ---
    floatx4 e0, e1;
    #pragma unroll
    for (int t = 0; t < 2; ++t) {
      floatx4 d4 = {0.f, 0.f, 0.f, 0.f};
      #pragma unroll
      for (int ks = 0; ks < 4; ++ks)
        d4 = __builtin_amdgcn_mfma_f32_16x16x32_bf16(bk[t][ks], aq[ks], d4, 0, 0, 0);
      floatx4 ev;
      #pragma unroll
      for (int r = 0; r < 4; ++r) {
        const int j = jb[t] + q * 4 + r;
        const float e = (tval[t] && j < NP) ? __expf(d4[r] - SHIFT) : 0.f;
        ev[r] = e;
        Ssum += e;
      }
      if (t == 0) e0 = ev; else e1 = ev;
    }

    // --- D-layout -> B-operand transform (R4/R6-verified packed exchange) ---
    short8 bp;
    #pragma unroll
    for (int r = 0; r < 4; ++r) {
      const uint32_t pe = pk2(e0[r], e1[r]);
      const int lo = __builtin_amdgcn_ds_bpermute(alo, (int)pe);
      const int hi = __builtin_amdgcn_ds_bpermute(alo + 64, (int)pe);
      bp[r]     = (short)(uint16_t)(hiTile ? (lo >> 16) : (lo & 0xFFFF));
      bp[4 + r] = (short)(uint16_t)(hiTile ? (hi >> 16) : (hi & 0xFFFF));
    }

    // --- PV: A=V (m=d), B=P (n=p) -> D row=d col=p ---
    #pragma unroll
    for (int dt = 0; dt < 8; ++dt)
      acc[dt] = __builtin_amdgcn_mfma_f32_16x16x32_bf16(av[dt], bp, acc[dt], 0, 0, 0);
  }

  // --- publish row sums and accumulators; single barrier ---
  {
    float sv = Ssum;
    sv += __shfl_xor(sv, 16);
    sv += __shfl_xor(sv, 32);
    if (lane < 16) sS[w][lane] = sv;
  }
  #pragma unroll
  for (int g = 0; g < 8; ++g)
    *(floatx4*)&mergeAcc[w][g][lane * 4] = acc[g];
  __syncthreads();

  float stot = 0.f;
  #pragma unroll
  for (int w2 = 0; w2 < 8; ++w2) stot += sS[w2][ln];
  const float inv = 1.f / stot;

  // wave w owns merged d-tile w: sum across the 8 source waves
  floatx4 v = *(const floatx4*)&mergeAcc[0][w][lane * 4];
  #pragma unroll
  for (int w2 = 1; w2 < 8; ++w2)
    v += *(const floatx4*)&mergeAcc[w2][w][lane * 4];

  const int pp = p0 + ln;
  if (pp < NP) {
    float* ob = out + ((size_t)(b * KCLS + kc) * ND + w * 16 + q * 4) * NP + pp;
    #pragma unroll
    for (int rr = 0; rr < 4; ++rr) ob[(size_t)rr * NP] = v[rr] * inv;
  }
}

// ---------------------------------------------------------------------------
extern "C" void kernel_launch(void* const* d_in, const int* in_sizes, int n_in,
                              void* d_out, int out_size, void* d_ws, size_t ws_size,
                              hipStream_t stream) {
  const float* supp   = (const float*)d_in[0];
  const float* qry    = (const float*)d_in[1];
  const int*   labels = (const int*)d_in[2];
  const float* Wqk    = (const float*)d_in[3];
  const float* Wv     = (const float*)d_in[4];
  float* out = (float*)d_out;

  // ws layout (~28 MB)
  uint16_t* Xhi = (uint16_t*)d_ws;
  uint16_t* Xlo = Xhi + (size_t)NIMG * JS * NC;
  uint16_t* Whi = Xlo + (size_t)NIMG * JS * NC;
  uint16_t* Wlo = Whi + (size_t)2 * ND * NC;
  uint16_t* Qt  = Wlo + (size_t)2 * ND * NC;        // [32][196][128]
  uint16_t* Kt  = Qt  + (size_t)NB * NP * ND;       // [25][208][128]
  uint16_t* Vt  = Kt  + (size_t)NSUP * JS * ND;     // [25][128][208]
  float* outVq = out + (size_t)NB * KCLS * ND * NP; // query_v_flat region

  conv_kernel<<<914, 256, 0, stream>>>(supp, qry, Wqk, Wv, Xhi, Xlo, Whi, Wlo);
  gemm_kernel<<<741, 256, 0, stream>>>(Xhi, Xlo, Whi, Wlo, Qt, Kt, Vt, outVq);
  attn_kernel<<<2080, 512, 0, stream>>>(Qt, Kt, Vt, labels, out);
}

// Round 8
// 174.139 us; speedup vs baseline: 1.4772x; 1.4772x over previous
//
#include <hip/hip_runtime.h>
#include <cstdint>
#include <cstddef>

// Problem constants
#define NB   32    // query batch
#define NSUP 25    // support images
#define KCLS 5     // classes
#define NC   512   // input channels
#define ND   128   // dk = dv
#define NP   196   // h*w
#define JS   208   // per-support padded spatial (13*16)
#define NIMG 57    // 32 query + 25 support
#define SHIFT 8.0f // fixed logit shift (softmax-invariant overflow guard)

typedef __attribute__((ext_vector_type(8))) short short8;   // 8 x bf16 (4 VGPRs)
typedef __attribute__((ext_vector_type(4))) float floatx4;  // MFMA C/D

__device__ inline short f2bf(float x) {
  union { float f; uint32_t u; } v; v.f = x;
  uint32_t r = (v.u + 0x7FFFu + ((v.u >> 16) & 1u)) >> 16;  // RNE
  return (short)(r & 0xFFFFu);
}
__device__ inline uint32_t pk2(float a, float b) {
  return (uint32_t)(uint16_t)f2bf(a) | ((uint32_t)(uint16_t)f2bf(b) << 16);
}

// ---------------------------------------------------------------------------
// Kernel 0: W fp32 -> bf16. Whi[mat][d:128][c:512], mats contiguous.
// grid = 64 x 256, 8 contiguous elements per thread (float4 x2 -> short8).
// ---------------------------------------------------------------------------
__global__ __launch_bounds__(256) void wconv_kernel(
    const float* __restrict__ Wqk, const float* __restrict__ Wv,
    uint16_t* __restrict__ Whi)
{
  const int f = (blockIdx.x * 256 + (int)threadIdx.x) * 8;   // < 131072
  const float* src = (f < ND * NC) ? (Wqk + f) : (Wv + f - ND * NC);
  short8 hv;
  #pragma unroll
  for (int i = 0; i < 8; ++i) hv[i] = f2bf(src[i]);
  *(short8*)(Whi + f) = hv;
}

// ---------------------------------------------------------------------------
// Kernel 1: fused projection GEMM (transpose staged in LDS, 1-term bf16).
// Block = (img, p-tile16); 4 waves = 4 d-quads (32 d each).
// LDS: X[c:512][p:16] fp32, pitch 17 (2-way banks = free).
// grid = 57*13 = 741 blocks x 256 threads.
//   QK: A=X(m=p), B=Wqk(n=d) -> bf16 Qt[b][p<196][d] / Kt[n][p:208][d]
//   V:  A=Wv(m=d), B=X(n=p)  -> bf16 Vt[n][d][p:208] / fp32 outVq[b][d][p]
// X fragment shared between both products (A for QK, B for V) — R4/R6-verified.
// ---------------------------------------------------------------------------
__global__ __launch_bounds__(256) void gemm_kernel(
    const float* __restrict__ supp, const float* __restrict__ qry,
    const uint16_t* __restrict__ Whi,
    uint16_t* __restrict__ Qt, uint16_t* __restrict__ Kt,
    uint16_t* __restrict__ Vt, float* __restrict__ outVq)
{
  __shared__ float xs[NC * 17];         // 34.8 KB
  const int bx = blockIdx.x;
  const int t16 = bx % 13, img = bx / 13;
  const int tid = (int)threadIdx.x;
  const int w = tid >> 6, lane = tid & 63, ln = lane & 15, q = lane >> 4;
  const int d0 = w * 32;
  const int p0 = t16 * 16;

  const float* __restrict__ X = (img < NB)
      ? (qry  + (size_t)img * NC * NP)
      : (supp + (size_t)(img - NB) * NC * NP);

  // stage X tile: [c][p] -> LDS (pad rows = copy of row 195)
  for (int idx = tid; idx < NC * 16; idx += 256) {
    const int c = idx >> 4, p = idx & 15;
    int pg = p0 + p; if (pg > NP - 1) pg = NP - 1;
    xs[c * 17 + p] = X[c * NP + pg];
  }
  __syncthreads();

  floatx4 aQ[2], aV[2];
  #pragma unroll
  for (int nt = 0; nt < 2; ++nt) {
    aQ[nt] = (floatx4){0.f, 0.f, 0.f, 0.f};
    aV[nt] = (floatx4){0.f, 0.f, 0.f, 0.f};
  }

  for (int ks = 0; ks < 16; ++ks) {
    // X fragment from LDS + convert: lane = p-row ln, k = q*8 + i
    short8 xh;
    #pragma unroll
    for (int i = 0; i < 8; ++i)
      xh[i] = f2bf(xs[(ks * 32 + q * 8 + i) * 17 + ln]);
    #pragma unroll
    for (int nt = 0; nt < 2; ++nt) {
      const size_t wr = (size_t)(d0 + nt * 16 + ln) * NC + ks * 32 + q * 8;
      const short8 wqh = *(const short8*)(Whi + wr);
      aQ[nt] = __builtin_amdgcn_mfma_f32_16x16x32_bf16(xh, wqh, aQ[nt], 0, 0, 0);
      const short8 wvh = *(const short8*)(Whi + (size_t)ND * NC + wr);
      aV[nt] = __builtin_amdgcn_mfma_f32_16x16x32_bf16(wvh, xh, aV[nt], 0, 0, 0);
    }
  }

  // QK: D row = p = p0+q*4+rr, col = d = d0+nt*16+ln
  if (img < NB) {
    #pragma unroll
    for (int nt = 0; nt < 2; ++nt)
      #pragma unroll
      for (int rr = 0; rr < 4; ++rr) {
        const int p = p0 + q * 4 + rr;
        if (p < NP)
          Qt[((size_t)img * NP + p) * ND + d0 + nt * 16 + ln] = (uint16_t)f2bf(aQ[nt][rr]);
      }
  } else {
    const int n = img - NB;
    #pragma unroll
    for (int nt = 0; nt < 2; ++nt)
      #pragma unroll
      for (int rr = 0; rr < 4; ++rr) {
        const int p = p0 + q * 4 + rr;              // 0..207, pads masked in attn
        Kt[((size_t)n * JS + p) * ND + d0 + nt * 16 + ln] = (uint16_t)f2bf(aQ[nt][rr]);
      }
  }
  // V: D row = d = d0+nt*16+q*4+rr, col = p = p0+ln
  const int p = p0 + ln;
  if (img < NB) {
    if (p < NP) {
      #pragma unroll
      for (int nt = 0; nt < 2; ++nt)
        #pragma unroll
        for (int rr = 0; rr < 4; ++rr)
          outVq[((size_t)img * ND + d0 + nt * 16 + q * 4 + rr) * NP + p] = aV[nt][rr];
    }
  } else {
    const int n = img - NB;
    #pragma unroll
    for (int nt = 0; nt < 2; ++nt)
      #pragma unroll
      for (int rr = 0; rr < 4; ++rr)
        Vt[((size_t)n * ND + d0 + nt * 16 + q * 4 + rr) * JS + p] = (uint16_t)f2bf(aV[nt][rr]);
  }
}

// ---------------------------------------------------------------------------
// Kernel 2: per-class masked attention (R6 verbatim — best measured, 70.9 us).
// Block = (b-pair, kc, p-tile16), 4 waves j-split; each wave serves BOTH
// batches of the pair from the same K/V fragments.
// grid = 16*5*13 = 1040 blocks x 256 threads.
// ---------------------------------------------------------------------------
__global__ __launch_bounds__(256, 2) void attn_kernel(
    const uint16_t* __restrict__ Qt, const uint16_t* __restrict__ Kt,
    const uint16_t* __restrict__ Vt, const int* __restrict__ labels,
    float* __restrict__ out)
{
  __shared__ float mergeAcc[4][4][256];   // 16 KB merge buffer
  __shared__ float sS[2][4][16];

  const int bx = blockIdx.x;              // 1040 = 16*5*13
  const int pt = bx % 13;
  const int rem = bx / 13;                // 80 = 16*5
  const int kc = rem % KCLS;
  const int b0 = (rem / KCLS) * 2;        // batch pair base
  const int p0 = pt * 16;
  const int tid = (int)threadIdx.x;
  const int w = tid >> 6, lane = tid & 63, ln = lane & 15, q = lane >> 4;

  // class-support list packed in a register (6 bits/slot) via ballot
  const int myl = (lane < NSUP) ? labels[lane] : -1;
  unsigned long long m = __ballot(myl == kc);
  int clsPack = 0;
  #pragma unroll
  for (int s = 0; s < 5; ++s) {
    const int n = (m != 0ull) ? (int)__builtin_ctzll(m) : 0;
    clsPack |= n << (6 * s);
    m &= (m - 1);
  }

  // Q B-frags (resident, per batch): B[n=p][k=d]
  short8 aq[2][4];
  #pragma unroll
  for (int bb = 0; bb < 2; ++bb) {
    int p = p0 + ln; if (p > NP - 1) p = NP - 1;
    const uint16_t* base = Qt + ((size_t)(b0 + bb) * NP + p) * ND + q * 8;
    #pragma unroll
    for (int ks = 0; ks < 4; ++ks) aq[bb][ks] = *(const short8*)(base + ks * 32);
  }

  floatx4 acc[2][8];
  #pragma unroll
  for (int bb = 0; bb < 2; ++bb)
    #pragma unroll
    for (int dt = 0; dt < 8; ++dt) acc[bb][dt] = (floatx4){0.f, 0.f, 0.f, 0.f};
  float Ssum[2] = {0.f, 0.f};

  const int alo = (ln + ((q & 1) << 5)) << 2;  // bpermute byte addr (R4-verified)
  const bool hiTile = (q >= 2);

  for (int it = w; it < 33; it += 4) {         // this wave's 32-col chunks
    // --- V B-frags (shared across batches): B[n=d][k=j] ---
    const int cc = it * 32 + q * 8;
    int s2 = cc / JS, j2 = cc - s2 * JS;
    if (s2 > 4) { s2 = 4; j2 = 192; }          // pad region: weights are 0
    const int n2 = (clsPack >> (6 * s2)) & 63;
    short8 av[8];
    #pragma unroll
    for (int dt = 0; dt < 8; ++dt)
      av[dt] = *(const short8*)(Vt + ((size_t)n2 * ND + dt * 16 + ln) * JS + j2);

    // --- K A-frags (shared): A[m=j][k=d], per 16-col tile ---
    short8 bk[2][4];
    int jb[2]; bool tval[2];
    #pragma unroll
    for (int t = 0; t < 2; ++t) {
      const int tile16 = it * 2 + t;
      int s = tile16 / 13;
      const int j0 = (tile16 - s * 13) * 16;
      tval[t] = (s < 5); jb[t] = j0;
      if (s > 4) s = 4;
      const int n = (clsPack >> (6 * s)) & 63;
      const uint16_t* kp = Kt + ((size_t)n * JS + j0 + ln) * ND + q * 8;
      #pragma unroll
      for (int ks = 0; ks < 4; ++ks) bk[t][ks] = *(const short8*)(kp + ks * 32);
    }

    // --- per batch: QK as S^T, exp, transform, PV ---
    #pragma unroll
    for (int bb = 0; bb < 2; ++bb) {
      floatx4 e0, e1;
      #pragma unroll
      for (int t = 0; t < 2; ++t) {
        floatx4 d4 = {0.f, 0.f, 0.f, 0.f};
        #pragma unroll
        for (int ks = 0; ks < 4; ++ks)
          d4 = __builtin_amdgcn_mfma_f32_16x16x32_bf16(bk[t][ks], aq[bb][ks], d4, 0, 0, 0);
        floatx4 ev;
        #pragma unroll
        for (int r = 0; r < 4; ++r) {
          const int j = jb[t] + q * 4 + r;
          const float e = (tval[t] && j < NP) ? __expf(d4[r] - SHIFT) : 0.f;
          ev[r] = e;
          Ssum[bb] += e;
        }
        if (t == 0) e0 = ev; else e1 = ev;
      }

      // D-layout -> B-operand transform (R4/R6-verified packed exchange)
      short8 bp;
      #pragma unroll
      for (int r = 0; r < 4; ++r) {
        const uint32_t pe = pk2(e0[r], e1[r]);
        const int lo = __builtin_amdgcn_ds_bpermute(alo, (int)pe);
        const int hi = __builtin_amdgcn_ds_bpermute(alo + 64, (int)pe);
        bp[r]     = (short)(uint16_t)(hiTile ? (lo >> 16) : (lo & 0xFFFF));
        bp[4 + r] = (short)(uint16_t)(hiTile ? (hi >> 16) : (hi & 0xFFFF));
      }

      // PV: A=V (m=d), B=P (n=p) -> D row=d col=p
      #pragma unroll
      for (int dt = 0; dt < 8; ++dt)
        acc[bb][dt] = __builtin_amdgcn_mfma_f32_16x16x32_bf16(av[dt], bp, acc[bb][dt], 0, 0, 0);
    }
  }

  // --- row-sum reduce (per batch) and publish ---
  #pragma unroll
  for (int bb = 0; bb < 2; ++bb) {
    float sv = Ssum[bb];
    sv += __shfl_xor(sv, 16);
    sv += __shfl_xor(sv, 32);
    if (lane < 16) sS[bb][w][lane] = sv;
  }
  __syncthreads();
  const float inv0 = 1.f / (sS[0][0][ln] + sS[0][1][ln] + sS[0][2][ln] + sS[0][3][ln]);
  const float inv1 = 1.f / (sS[1][0][ln] + sS[1][1][ln] + sS[1][2][ln] + sS[1][3][ln]);
  const int pp = p0 + ln;

  // --- merge across 4 j-split waves: 4 rounds of 4 d-tiles ---
  for (int rd = 0; rd < 4; ++rd) {
    const int bb = rd >> 1, hf = rd & 1;
    #pragma unroll
    for (int g = 0; g < 4; ++g)
      *(floatx4*)&mergeAcc[g][w][lane * 4] = acc[bb][hf * 4 + g];
    __syncthreads();
    floatx4 v = *(const floatx4*)&mergeAcc[w][0][lane * 4];
    v += *(const floatx4*)&mergeAcc[w][1][lane * 4];
    v += *(const floatx4*)&mergeAcc[w][2][lane * 4];
    v += *(const floatx4*)&mergeAcc[w][3][lane * 4];
    if (pp < NP) {
      const float inv = bb ? inv1 : inv0;
      const int dtile = hf * 4 + w;                // this wave's merged d-tile
      float* ob = out + ((size_t)((b0 + bb) * KCLS + kc) * ND + dtile * 16 + q * 4) * NP + pp;
      #pragma unroll
      for (int rr = 0; rr < 4; ++rr) ob[(size_t)rr * NP] = v[rr] * inv;
    }
    __syncthreads();
  }
}

// ---------------------------------------------------------------------------
extern "C" void kernel_launch(void* const* d_in, const int* in_sizes, int n_in,
                              void* d_out, int out_size, void* d_ws, size_t ws_size,
                              hipStream_t stream) {
  const float* supp   = (const float*)d_in[0];
  const float* qry    = (const float*)d_in[1];
  const int*   labels = (const int*)d_in[2];
  const float* Wqk    = (const float*)d_in[3];
  const float* Wv     = (const float*)d_in[4];
  float* out = (float*)d_out;

  // ws layout (~4.6 MB)
  uint16_t* Whi = (uint16_t*)d_ws;                  // [2][128][512]
  uint16_t* Qt  = Whi + (size_t)2 * ND * NC;        // [32][196][128]
  uint16_t* Kt  = Qt  + (size_t)NB * NP * ND;       // [25][208][128]
  uint16_t* Vt  = Kt  + (size_t)NSUP * JS * ND;     // [25][128][208]
  float* outVq = out + (size_t)NB * KCLS * ND * NP; // query_v_flat region

  wconv_kernel<<<64, 256, 0, stream>>>(Wqk, Wv, Whi);
  gemm_kernel<<<741, 256, 0, stream>>>(supp, qry, Whi, Qt, Kt, Vt, outVq);
  attn_kernel<<<1040, 256, 0, stream>>>(Qt, Kt, Vt, labels, out);
}

// Round 9
// 161.058 us; speedup vs baseline: 1.5972x; 1.0812x over previous
//
#include <hip/hip_runtime.h>
#include <cstdint>
#include <cstddef>

// Problem constants
#define NB   32    // query batch
#define NSUP 25    // support images
#define KCLS 5     // classes
#define NC   512   // input channels
#define ND   128   // dk = dv
#define NP   196   // h*w
#define JS   208   // per-support padded spatial (13*16)
#define SHIFT 8.0f // fixed logit shift (softmax-invariant overflow guard)

// attn LDS staging geometry
#define KPITCH 272             // 256B K row + 16B pad (bank-stride 68 dw -> 2-way)
#define KTILE  (16 * KPITCH)   // 4352 B per 16-j K tile
#define KBUF   (2 * KTILE)     // 8704 B
#define VPITCH 80              // 64B V row + 16B pad (bank-stride 20 dw -> 2-way)
#define VBUF   (128 * VPITCH)  // 10240 B
#define BUFSZ  (KBUF + VBUF)   // 18944 B per buffer

typedef __attribute__((ext_vector_type(8))) short short8;   // 8 x bf16 (4 VGPRs)
typedef __attribute__((ext_vector_type(4))) float floatx4;  // MFMA C/D

__device__ inline short f2bf(float x) {
  union { float f; uint32_t u; } v; v.f = x;
  uint32_t r = (v.u + 0x7FFFu + ((v.u >> 16) & 1u)) >> 16;  // RNE
  return (short)(r & 0xFFFFu);
}
__device__ inline uint32_t pk2(float a, float b) {
  return (uint32_t)(uint16_t)f2bf(a) | ((uint32_t)(uint16_t)f2bf(b) << 16);
}

// ---------------------------------------------------------------------------
// Kernel 0: W fp32 -> bf16. Whi[mat][d:128][c:512], mats contiguous.
// ---------------------------------------------------------------------------
__global__ __launch_bounds__(256) void wconv_kernel(
    const float* __restrict__ Wqk, const float* __restrict__ Wv,
    uint16_t* __restrict__ Whi)
{
  const int f = (blockIdx.x * 256 + (int)threadIdx.x) * 8;   // < 131072
  const float* src = (f < ND * NC) ? (Wqk + f) : (Wv + f - ND * NC);
  short8 hv;
  #pragma unroll
  for (int i = 0; i < 8; ++i) hv[i] = f2bf(src[i]);
  *(short8*)(Whi + f) = hv;
}

// ---------------------------------------------------------------------------
// Kernel 1: fused projection GEMM. X tile staged as BF16 in LDS ([p][c],
// pitch 520 -> 2-way banks) so each X fragment is ONE ds_read_b128 (R8 used
// 8 scalar ds_read_b32 + 8 f2bf per fragment — the gemm bottleneck).
// Block = (img, p-tile16); 4 waves = 4 d-quads. grid = 57*13 = 741 x 256.
//   QK: A=X(m=p), B=Wqk(n=d) -> bf16 Qt[b][p<196][d] / Kt[n][p:208][d]
//   V:  A=Wv(m=d), B=X(n=p)  -> bf16 Vt[n][d][p:208] / fp32 outVq[b][d][p]
// ---------------------------------------------------------------------------
__global__ __launch_bounds__(256) void gemm_kernel(
    const float* __restrict__ supp, const float* __restrict__ qry,
    const uint16_t* __restrict__ Whi,
    uint16_t* __restrict__ Qt, uint16_t* __restrict__ Kt,
    uint16_t* __restrict__ Vt, float* __restrict__ outVq)
{
  __shared__ uint16_t xs[16 * 520];     // 16.6 KB bf16 X tile, [p][c+pad]
  const int bx = blockIdx.x;
  const int t16 = bx % 13, img = bx / 13;
  const int tid = (int)threadIdx.x;
  const int w = tid >> 6, lane = tid & 63, ln = lane & 15, q = lane >> 4;
  const int d0 = w * 32;
  const int p0 = t16 * 16;

  const float* __restrict__ X = (img < NB)
      ? (qry  + (size_t)img * NC * NP)
      : (supp + (size_t)(img - NB) * NC * NP);

  // stage X tile as bf16: read float4 along p, write packed pairs along c
  #pragma unroll
  for (int k = 0; k < 4; ++k) {
    const int id = k * 256 + tid;
    const int cp = id >> 2;                        // c-pair: c = 2cp, 2cp+1
    const int pq = id & 3;
    int pg = p0 + pq * 4; if (pg > NP - 4) pg = NP - 4;   // clamp (pad rows masked later)
    const floatx4 fa = *(const floatx4*)(X + (2 * cp) * NP + pg);
    const floatx4 fb = *(const floatx4*)(X + (2 * cp + 1) * NP + pg);
    #pragma unroll
    for (int i = 0; i < 4; ++i)
      *((uint32_t*)xs + (pq * 4 + i) * 260 + cp) = pk2(fa[i], fb[i]);
  }
  __syncthreads();

  floatx4 aQ[2], aV[2];
  #pragma unroll
  for (int nt = 0; nt < 2; ++nt) {
    aQ[nt] = (floatx4){0.f, 0.f, 0.f, 0.f};
    aV[nt] = (floatx4){0.f, 0.f, 0.f, 0.f};
  }

  for (int ks = 0; ks < 16; ++ks) {
    const short8 xh = *(const short8*)&xs[ln * 520 + ks * 32 + q * 8];  // 1 ds_read_b128
    #pragma unroll
    for (int nt = 0; nt < 2; ++nt) {
      const size_t wr = (size_t)(d0 + nt * 16 + ln) * NC + ks * 32 + q * 8;
      const short8 wqh = *(const short8*)(Whi + wr);
      aQ[nt] = __builtin_amdgcn_mfma_f32_16x16x32_bf16(xh, wqh, aQ[nt], 0, 0, 0);
      const short8 wvh = *(const short8*)(Whi + (size_t)ND * NC + wr);
      aV[nt] = __builtin_amdgcn_mfma_f32_16x16x32_bf16(wvh, xh, aV[nt], 0, 0, 0);
    }
  }

  // QK: D row = p = p0+q*4+rr, col = d = d0+nt*16+ln
  if (img < NB) {
    #pragma unroll
    for (int nt = 0; nt < 2; ++nt)
      #pragma unroll
      for (int rr = 0; rr < 4; ++rr) {
        const int p = p0 + q * 4 + rr;
        if (p < NP)
          Qt[((size_t)img * NP + p) * ND + d0 + nt * 16 + ln] = (uint16_t)f2bf(aQ[nt][rr]);
      }
  } else {
    const int n = img - NB;
    #pragma unroll
    for (int nt = 0; nt < 2; ++nt)
      #pragma unroll
      for (int rr = 0; rr < 4; ++rr) {
        const int p = p0 + q * 4 + rr;              // 0..207, pads masked in attn
        Kt[((size_t)n * JS + p) * ND + d0 + nt * 16 + ln] = (uint16_t)f2bf(aQ[nt][rr]);
      }
  }
  // V: D row = d = d0+nt*16+q*4+rr, col = p = p0+ln
  const int p = p0 + ln;
  if (img < NB) {
    if (p < NP) {
      #pragma unroll
      for (int nt = 0; nt < 2; ++nt)
        #pragma unroll
        for (int rr = 0; rr < 4; ++rr)
          outVq[((size_t)img * ND + d0 + nt * 16 + q * 4 + rr) * NP + p] = aV[nt][rr];
    }
  } else {
    const int n = img - NB;
    #pragma unroll
    for (int nt = 0; nt < 2; ++nt)
      #pragma unroll
      for (int rr = 0; rr < 4; ++rr)
        Vt[((size_t)n * ND + d0 + nt * 16 + q * 4 + rr) * JS + p] = (uint16_t)f2bf(aV[nt][rr]);
  }
}

// ---------------------------------------------------------------------------
// Kernel 2: per-class masked attention with block-level double-buffered LDS
// K/V staging. Block = (b-quad, kc, p-tile16): 4 waves, wave w owns batch
// b0+w END-TO-END (all 33 chunks) — no cross-wave merge. All 256 threads
// cooperatively stage each chunk's K (2x16j x 128d) and V (128d x 32j) into
// LDS (fully coalesced 16B/lane loads); frag reads are ds_read_b128 on
// padded pitches (2-way banks = free). Frag values bit-identical to R6;
// exp/bpermute/PV math is R6-verbatim. grid = 8*5*13 = 520 x 256.
// ---------------------------------------------------------------------------
__global__ __launch_bounds__(256, 2) void attn_kernel(
    const uint16_t* __restrict__ Qt, const uint16_t* __restrict__ Kt,
    const uint16_t* __restrict__ Vt, const int* __restrict__ labels,
    float* __restrict__ out)
{
  __shared__ __align__(16) char smem[2 * BUFSZ];   // 37.9 KB double buffer

  const int bx = blockIdx.x;              // 520 = 8*5*13
  const int pt = bx % 13;
  const int rem = bx / 13;                // 40 = 8*5
  const int kc = rem % KCLS;
  const int b0 = (rem / KCLS) * 4;        // batch quad base
  const int p0 = pt * 16;
  const int tid = (int)threadIdx.x;
  const int w = tid >> 6, lane = tid & 63, ln = lane & 15, q = lane >> 4;
  const int b = b0 + w;                   // this wave's batch

  // class-support list packed in a register (6 bits/slot) via ballot
  const int myl = (lane < NSUP) ? labels[lane] : -1;
  unsigned long long m = __ballot(myl == kc);
  int clsPack = 0;
  #pragma unroll
  for (int s = 0; s < 5; ++s) {
    const int n = (m != 0ull) ? (int)__builtin_ctzll(m) : 0;
    clsPack |= n << (6 * s);
    m &= (m - 1);
  }

  // Q B-frags (resident): B[n=p][k=d]
  short8 aq[4];
  {
    int p = p0 + ln; if (p > NP - 1) p = NP - 1;
    const uint16_t* base = Qt + ((size_t)b * NP + p) * ND + q * 8;
    #pragma unroll
    for (int ks = 0; ks < 4; ++ks) aq[ks] = *(const short8*)(base + ks * 32);
  }

  floatx4 acc[8];
  #pragma unroll
  for (int dt = 0; dt < 8; ++dt) acc[dt] = (floatx4){0.f, 0.f, 0.f, 0.f};
  float Ssum = 0.f;

  const int alo = (ln + ((q & 1) << 5)) << 2;  // bpermute byte addr (R4/R6-verified)
  const bool hiTile = (q >= 2);

  // ---- chunk staging helpers (wave-uniform params, per-thread 4 slots) ----
  // K: slots 0..511:  t=slot>>8, r=(slot>>4)&15, sc=slot&15
  // V: slots 512..1023: h, d, sc2 -> scol = h*2+sc2
  int4 pf[4];
  {
    // prefetch chunk 0
    int nk[2], j0k[2], nv[2], jv[2];
    #pragma unroll
    for (int t = 0; t < 2; ++t) {
      const int tile16 = t;             // cn = 0
      int s = tile16 / 13;
      j0k[t] = (tile16 - s * 13) * 16;
      if (s > 4) s = 4;
      nk[t] = (clsPack >> (6 * s)) & 63;
    }
    #pragma unroll
    for (int h = 0; h < 2; ++h) {
      const int ch = h * 16;
      int sv = ch / JS, jvv = ch - sv * JS;
      if (sv > 4) { sv = 4; jvv = 192; }
      nv[h] = (clsPack >> (6 * sv)) & 63;
      jv[h] = jvv;
    }
    #pragma unroll
    for (int pass = 0; pass < 4; ++pass) {
      const int slot = pass * 256 + tid;
      if (pass < 2) {
        const int t = slot >> 8, r = (slot >> 4) & 15, sc = slot & 15;
        pf[pass] = *(const int4*)(Kt + ((size_t)(nk[t] * JS + j0k[t] + r)) * ND + sc * 8);
      } else {
        const int vs = slot - 512;
        const int h = vs >> 8, d = (vs >> 1) & 127, sc2 = vs & 1;
        pf[pass] = *(const int4*)(Vt + ((size_t)(nv[h] * ND + d)) * JS + jv[h] + sc2 * 8);
      }
    }
    char* db = smem;                    // buffer 0
    #pragma unroll
    for (int pass = 0; pass < 4; ++pass) {
      const int slot = pass * 256 + tid;
      if (pass < 2) {
        const int t = slot >> 8, r = (slot >> 4) & 15, sc = slot & 15;
        *(int4*)(db + t * KTILE + r * KPITCH + sc * 16) = pf[pass];
      } else {
        const int vs = slot - 512;
        const int h = vs >> 8, d = (vs >> 1) & 127, sc2 = vs & 1;
        *(int4*)(db + KBUF + d * VPITCH + (h * 2 + sc2) * 16) = pf[pass];
      }
    }
  }
  __syncthreads();

  for (int it = 0; it < 33; ++it) {
    const int nb = it + 1;
    int nk[2], j0k[2], nv[2], jv[2];
    if (nb < 33) {                      // issue next chunk's global loads early
      #pragma unroll
      for (int t = 0; t < 2; ++t) {
        const int tile16 = nb * 2 + t;
        int s = tile16 / 13;
        j0k[t] = (tile16 - s * 13) * 16;
        if (s > 4) s = 4;
        nk[t] = (clsPack >> (6 * s)) & 63;
      }
      #pragma unroll
      for (int h = 0; h < 2; ++h) {
        const int ch = nb * 32 + h * 16;
        int sv = ch / JS, jvv = ch - sv * JS;
        if (sv > 4) { sv = 4; jvv = 192; }
        nv[h] = (clsPack >> (6 * sv)) & 63;
        jv[h] = jvv;
      }
      #pragma unroll
      for (int pass = 0; pass < 4; ++pass) {
        const int slot = pass * 256 + tid;
        if (pass < 2) {
          const int t = slot >> 8, r = (slot >> 4) & 15, sc = slot & 15;
          pf[pass] = *(const int4*)(Kt + ((size_t)(nk[t] * JS + j0k[t] + r)) * ND + sc * 8);
        } else {
          const int vs = slot - 512;
          const int h = vs >> 8, d = (vs >> 1) & 127, sc2 = vs & 1;
          pf[pass] = *(const int4*)(Vt + ((size_t)(nv[h] * ND + d)) * JS + jv[h] + sc2 * 8);
        }
      }
    }

    // ---- compute chunk `it` from buffer it&1 ----
    const char* kb = smem + (it & 1) * BUFSZ;
    const char* vb = kb + KBUF;

    short8 av[8];
    #pragma unroll
    for (int dt = 0; dt < 8; ++dt)
      av[dt] = *(const short8*)(vb + (dt * 16 + ln) * VPITCH + q * 16);

    short8 bk[2][4];
    #pragma unroll
    for (int t = 0; t < 2; ++t)
      #pragma unroll
      for (int ks = 0; ks < 4; ++ks)
        bk[t][ks] = *(const short8*)(kb + t * KTILE + ln * KPITCH + ks * 64 + q * 16);

    // QK as S^T (A=K m=j, B=Q n=p), exp with pad masking (R6 verbatim)
    floatx4 e0, e1;
    #pragma unroll
    for (int t = 0; t < 2; ++t) {
      const int tile16 = it * 2 + t;
      const int s = tile16 / 13;
      const int j0 = (tile16 - s * 13) * 16;
      const bool tval = (s < 5);
      floatx4 d4 = {0.f, 0.f, 0.f, 0.f};
      #pragma unroll
      for (int ks = 0; ks < 4; ++ks)
        d4 = __builtin_amdgcn_mfma_f32_16x16x32_bf16(bk[t][ks], aq[ks], d4, 0, 0, 0);
      floatx4 ev;
      #pragma unroll
      for (int r = 0; r < 4; ++r) {
        const int j = j0 + q * 4 + r;
        const float e = (tval && j < NP) ? __expf(d4[r] - SHIFT) : 0.f;
        ev[r] = e;
        Ssum += e;
      }
      if (t == 0) e0 = ev; else e1 = ev;
    }

    // D-layout -> B-operand transform (R4/R6-verified packed exchange)
    short8 bp;
    #pragma unroll
    for (int r = 0; r < 4; ++r) {
      const uint32_t pe = pk2(e0[r], e1[r]);
      const int lo = __builtin_amdgcn_ds_bpermute(alo, (int)pe);
      const int hi = __builtin_amdgcn_ds_bpermute(alo + 64, (int)pe);
      bp[r]     = (short)(uint16_t)(hiTile ? (lo >> 16) : (lo & 0xFFFF));
      bp[4 + r] = (short)(uint16_t)(hiTile ? (hi >> 16) : (hi & 0xFFFF));
    }

    // PV: A=V (m=d), B=P (n=p) -> D row=d col=p
    #pragma unroll
    for (int dt = 0; dt < 8; ++dt)
      acc[dt] = __builtin_amdgcn_mfma_f32_16x16x32_bf16(av[dt], bp, acc[dt], 0, 0, 0);

    // ---- write next chunk to the other buffer ----
    if (nb < 33) {
      char* db = smem + (nb & 1) * BUFSZ;
      #pragma unroll
      for (int pass = 0; pass < 4; ++pass) {
        const int slot = pass * 256 + tid;
        if (pass < 2) {
          const int t = slot >> 8, r = (slot >> 4) & 15, sc = slot & 15;
          *(int4*)(db + t * KTILE + r * KPITCH + sc * 16) = pf[pass];
        } else {
          const int vs = slot - 512;
          const int h = vs >> 8, d = (vs >> 1) & 127, sc2 = vs & 1;
          *(int4*)(db + KBUF + d * VPITCH + (h * 2 + sc2) * 16) = pf[pass];
        }
      }
    }
    __syncthreads();
  }

  // ---- normalize and store (per wave; no merge needed) ----
  float sv = Ssum;
  sv += __shfl_xor(sv, 16);
  sv += __shfl_xor(sv, 32);
  const float inv = 1.f / sv;
  const int pp = p0 + ln;
  if (pp < NP) {
    float* ob = out + ((size_t)(b * KCLS + kc) * ND + q * 4) * NP + pp;
    #pragma unroll
    for (int dt = 0; dt < 8; ++dt)
      #pragma unroll
      for (int rr = 0; rr < 4; ++rr)
        ob[(size_t)(dt * 16 + rr) * NP] = acc[dt][rr] * inv;
  }
}

// ---------------------------------------------------------------------------
extern "C" void kernel_launch(void* const* d_in, const int* in_sizes, int n_in,
                              void* d_out, int out_size, void* d_ws, size_t ws_size,
                              hipStream_t stream) {
  const float* supp   = (const float*)d_in[0];
  const float* qry    = (const float*)d_in[1];
  const int*   labels = (const int*)d_in[2];
  const float* Wqk    = (const float*)d_in[3];
  const float* Wv     = (const float*)d_in[4];
  float* out = (float*)d_out;

  // ws layout (~4.6 MB)
  uint16_t* Whi = (uint16_t*)d_ws;                  // [2][128][512]
  uint16_t* Qt  = Whi + (size_t)2 * ND * NC;        // [32][196][128]
  uint16_t* Kt  = Qt  + (size_t)NB * NP * ND;       // [25][208][128]
  uint16_t* Vt  = Kt  + (size_t)NSUP * JS * ND;     // [25][128][208]
  float* outVq = out + (size_t)NB * KCLS * ND * NP; // query_v_flat region

  wconv_kernel<<<64, 256, 0, stream>>>(Wqk, Wv, Whi);
  gemm_kernel<<<741, 256, 0, stream>>>(supp, qry, Whi, Qt, Kt, Vt, outVq);
  attn_kernel<<<520, 256, 0, stream>>>(Qt, Kt, Vt, labels, out);
}